// Round 6
// baseline (378.775 us; speedup 1.0000x reference)
//
#include <hip/hip_runtime.h>
#include <hip/hip_fp16.h>

// DCell forward, MI355X (gfx950). All inputs/outputs fp32.
// R6: the layout-invariant ~102us stage3 was HBM row-buffer thrash from
// column-wise gene access (256-B fragments at 512-KB stride). Fix: dedicated
// transpose kernels stream genes in storage order (1-KB dense bursts) into
// term-major fp16 gT[t][b][64]; compute kernels then read genes as dense
// lane-contiguous 128-B rows. Weights via LDS fp16-pair broadcast + dot2 (R5).
// BatchNorm stays block-local (one block per term x D-chunk); bias cancels.
// ws: [gT3 67MB | gT2 16.8 | gT1 4.2 | h3 21 | h2 5.2 | h1 2.6 | z0p] ~117 MB.

#define DEV static __device__ __forceinline__

constexpr int B_  = 256, G_ = 64, D_ = 20;
constexpr int T3_ = 2048, T2_ = 512, T1_ = 128;
constexpr float EPS_ = 1e-5f;
constexpr int INM = 4 * D_ + G_;   // 144

constexpr size_t OFF_GT3 = 0;
constexpr size_t SZ_GT3 = (size_t)T3_ * B_ * G_ * 2;
constexpr size_t OFF_GT2 = OFF_GT3 + SZ_GT3;
constexpr size_t SZ_GT2 = (size_t)T2_ * B_ * G_ * 2;
constexpr size_t OFF_GT1 = OFF_GT2 + SZ_GT2;
constexpr size_t SZ_GT1 = (size_t)T1_ * B_ * G_ * 2;
constexpr size_t OFF_H3B = OFF_GT1 + SZ_GT1;
constexpr size_t SZ_H3 = (size_t)T3_ * B_ * D_ * 2;
constexpr size_t OFF_H2B = OFF_H3B + SZ_H3;
constexpr size_t SZ_H2 = (size_t)T2_ * B_ * D_ * 2;
constexpr size_t OFF_H1B = OFF_H2B + SZ_H2;
constexpr size_t SZ_H1 = (size_t)B_ * T1_ * D_ * 4;
constexpr size_t OFF_Z0B = OFF_H1B + SZ_H1;

typedef _Float16 hf2 __attribute__((ext_vector_type(2)));

DEV float dot2f(uint xu, uint wu, float c) {
#if __has_builtin(__builtin_amdgcn_fdot2)
    return __builtin_amdgcn_fdot2(__builtin_bit_cast(hf2, xu),
                                  __builtin_bit_cast(hf2, wu), c, false);
#else
    union { uint u; __half2 h; } X, W;
    X.u = xu; W.u = wu;
    c = fmaf(__low2float(X.h),  __low2float(W.h),  c);
    return fmaf(__high2float(X.h), __high2float(W.h), c);
#endif
}

DEV float fast_tanh(float x) {
    float e = __expf(2.0f * x);
    return fmaf(-2.0f, __builtin_amdgcn_rcpf(e + 1.0f), 1.0f);
}

// ---- transpose: genes fp32 [256][T][64] -> gT fp16 [t][b][64] ---------------
// Tile: 64 b x 4 t. Reads 1-KB dense bursts, writes 4-KB dense bursts.
template <int T>
__global__ __launch_bounds__(256, 4) void k_transpose(const float* __restrict__ genes,
                                                      __half* __restrict__ gT) {
    __shared__ uint lds[64 * 4 * 33];  // (b_loc*4+t) rows of 32 uints + 1 pad
    const int b0 = (blockIdx.x & 3) * 64;
    const int t0 = (blockIdx.x >> 2) * 4;
    const int tid = threadIdx.x, w = tid >> 6, l = tid & 63;
#pragma unroll
    for (int i = 0; i < 16; ++i) {
        const int b_loc = w * 16 + i;
        // slice genes[b0+b_loc][t0:t0+4][0:64] = 1024 floats; lane l takes float4 #l
        float4 f = ((const float4*)(genes + ((size_t)(b0 + b_loc) * T + t0) * G_))[l];
        const int t = l >> 4, g4 = l & 15;
        union { __half2 h; uint u; } a, c;
        a.h = __floats2half2_rn(f.x, f.y);
        c.h = __floats2half2_rn(f.z, f.w);
        uint* row = lds + (b_loc * 4 + t) * 33;
        row[2 * g4]     = a.u;
        row[2 * g4 + 1] = c.u;
    }
    __syncthreads();
#pragma unroll
    for (int r = 0; r < 8; ++r) {
        const int M = tid + 256 * r;           // 2048 output uint4s
        const int t = M >> 9, b = (M >> 3) & 63, u4 = M & 7;
        const uint* row = lds + (b * 4 + t) * 33 + 4 * u4;
        uint4 v = make_uint4(row[0], row[1], row[2], row[3]);
        ((uint4*)(gT + (((size_t)(t0 + t) * B_) + b0 + b) * G_))[u4] = v;
    }
}

// ---- weights W[k][o] fp32 -> LDS uint[p][oo] = half2(W[2p][o0+oo], W[2p+1][o0+oo])
template <int NP, int DCH>
DEV void stage_weights(const float* __restrict__ Wt, int o0, uint* ldsw, int tid) {
    constexpr int NU = NP * DCH;
#pragma unroll
    for (int j0 = 0; j0 < NU; j0 += 256) {
        int j = j0 + tid;
        if (NU % 256 != 0 && j >= NU) break;
        int p = j / DCH, oo = j - p * DCH;
        float w0 = Wt[(2 * p) * D_ + o0 + oo];
        float w1 = Wt[(2 * p + 1) * D_ + o0 + oo];
        union { __half2 h2; uint u; } pk;
        pk.h2 = __floats2half2_rn(w0, w1);
        ldsw[j] = pk.u;
    }
}

template <int DCH>
DEV void load_wrow(const uint* ldsw, int p, uint (&w)[DCH]) {
    const uint* row = ldsw + p * DCH;
    if constexpr (DCH % 4 == 0) {
#pragma unroll
        for (int v = 0; v < DCH / 4; ++v) {
            uint4 u = ((const uint4*)row)[v];
            w[4 * v] = u.x; w[4 * v + 1] = u.y; w[4 * v + 2] = u.z; w[4 * v + 3] = u.w;
        }
    } else {
#pragma unroll
        for (int v = 0; v < DCH / 2; ++v) {
            uint2 u = ((const uint2*)row)[v];
            w[2 * v] = u.x; w[2 * v + 1] = u.y;
        }
        if constexpr (DCH % 2 != 0) w[DCH - 1] = row[DCH - 1];
    }
}

// ---- BN over batch (block-local) + tanh -------------------------------------
template <int N>
DEV void bn_tanh(const float (&acc)[N], const float* gterm, const float* beterm,
                 int o0, int tid, float (&h)[N]) {
    __shared__ float sred[4][N], qred[4][N], Avec[N], Cvec[N];
    const int lane = tid & 63, wave = tid >> 6;
    float s[N], q[N];
#pragma unroll
    for (int o = 0; o < N; ++o) { s[o] = acc[o]; q[o] = acc[o] * acc[o]; }
#pragma unroll
    for (int off = 32; off; off >>= 1) {
#pragma unroll
        for (int o = 0; o < N; ++o) {
            s[o] += __shfl_xor(s[o], off, 64);
            q[o] += __shfl_xor(q[o], off, 64);
        }
    }
    if (lane == 0) {
#pragma unroll
        for (int o = 0; o < N; ++o) { sred[wave][o] = s[o]; qred[wave][o] = q[o]; }
    }
    __syncthreads();
    if (tid < N) {
        float S = sred[0][tid] + sred[1][tid] + sred[2][tid] + sred[3][tid];
        float Q = qred[0][tid] + qred[1][tid] + qred[2][tid] + qred[3][tid];
        float mu  = S * (1.0f / B_);
        float var = fmaxf(Q * (1.0f / B_) - mu * mu, 0.0f);
        float rstd = rsqrtf(var + EPS_);
        float A = rstd * gterm[o0 + tid];
        Avec[tid] = A;
        Cvec[tid] = beterm[o0 + tid] - mu * A;
    }
    __syncthreads();
#pragma unroll
    for (int o = 0; o < N; ++o) h[o] = fast_tanh(fmaf(acc[o], Avec[o], Cvec[o]));
}

// ---- stratum 3: x = gene row (dense 128 B per thread from gT3) --------------
__global__ __launch_bounds__(256, 4) void k_stage3(const __half* __restrict__ gT,
                                                   const float* __restrict__ W,
                                                   const float* __restrict__ g,
                                                   const float* __restrict__ be,
                                                   __half* __restrict__ hout) {
    __shared__ uint ldsw[(G_ / 2) * D_];       // 32 pairs x 20
    const int t = blockIdx.x, b = threadIdx.x;
    uint x[G_ / 2];
    const uint4* xp = (const uint4*)(gT + ((size_t)t * B_ + b) * G_);
#pragma unroll
    for (int v = 0; v < G_ / 8; ++v) {
        uint4 u = xp[v];
        x[4 * v] = u.x; x[4 * v + 1] = u.y; x[4 * v + 2] = u.z; x[4 * v + 3] = u.w;
    }
    stage_weights<G_ / 2, D_>(W + (size_t)t * (G_ * D_), 0, ldsw, b);
    __syncthreads();
    float acc[D_] = {};
#pragma unroll
    for (int p = 0; p < G_ / 2; ++p) {
        uint w[D_];
        load_wrow<D_>(ldsw, p, w);
#pragma unroll
        for (int o = 0; o < D_; ++o) acc[o] = dot2f(x[p], w[o], acc[o]);
    }
    float h[D_];
    bn_tanh<D_>(acc, g + (size_t)t * D_, be + (size_t)t * D_, 0, b, h);
    uint2* dst = (uint2*)(hout + ((size_t)t * B_ + b) * D_);
#pragma unroll
    for (int v = 0; v < 5; ++v) {
        union { __half2 h2[2]; uint2 u; } pk;
        pk.h2[0] = __floats2half2_rn(h[4 * v],     h[4 * v + 1]);
        pk.h2[1] = __floats2half2_rn(h[4 * v + 2], h[4 * v + 3]);
        dst[v] = pk.u;
    }
}

// ---- strata 2/1: x = [4 fp16 children (80) | gene row (64)] -----------------
template <int T, int DCH, bool OUT_HALF_TERM_MAJOR>
__global__ __launch_bounds__(256, 4) void k_mid(const __half* __restrict__ hsrc,
                                                const __half* __restrict__ gT,
                                                const float* __restrict__ W,
                                                const float* __restrict__ g,
                                                const float* __restrict__ be,
                                                void* __restrict__ hout_) {
    constexpr int NCH = D_ / DCH;
    constexpr int NP = INM / 2;                // 72 pairs: children 0..39, genes 40..71
    __shared__ uint ldsw[NP * DCH];
    const int t = blockIdx.x / NCH, o0 = (blockIdx.x % NCH) * DCH;
    const int b = threadIdx.x;
    uint xg[G_ / 2];
    const uint4* xp = (const uint4*)(gT + ((size_t)t * B_ + b) * G_);
#pragma unroll
    for (int v = 0; v < G_ / 8; ++v) {
        uint4 u = xp[v];
        xg[4 * v] = u.x; xg[4 * v + 1] = u.y; xg[4 * v + 2] = u.z; xg[4 * v + 3] = u.w;
    }
    stage_weights<NP, DCH>(W + (size_t)t * (INM * D_), o0, ldsw, b);
    __syncthreads();

    float acc[DCH] = {};
#pragma unroll
    for (int c = 0; c < 4; ++c) {
        const uint2* hp = (const uint2*)(hsrc + ((size_t)(4 * t + c) * B_ + b) * D_);
        uint xc[10];
#pragma unroll
        for (int v = 0; v < 5; ++v) {
            uint2 u = hp[v];
            xc[2 * v] = u.x; xc[2 * v + 1] = u.y;
        }
#pragma unroll
        for (int v = 0; v < 10; ++v) {
            uint w[DCH];
            load_wrow<DCH>(ldsw, c * 10 + v, w);
#pragma unroll
            for (int o = 0; o < DCH; ++o) acc[o] = dot2f(xc[v], w[o], acc[o]);
        }
    }
#pragma unroll
    for (int p = 0; p < G_ / 2; ++p) {
        uint w[DCH];
        load_wrow<DCH>(ldsw, 40 + p, w);
#pragma unroll
        for (int o = 0; o < DCH; ++o) acc[o] = dot2f(xg[p], w[o], acc[o]);
    }
    float h[DCH];
    bn_tanh<DCH>(acc, g + (size_t)t * D_, be + (size_t)t * D_, o0, b, h);
    if (OUT_HALF_TERM_MAJOR) {
        __half* hout = (__half*)hout_;
        uint* dst = (uint*)(hout + ((size_t)t * B_ + b) * D_ + o0);
#pragma unroll
        for (int v = 0; v < DCH / 2; ++v) {
            union { __half2 h2; uint u; } pk;
            pk.h2 = __floats2half2_rn(h[2 * v], h[2 * v + 1]);
            dst[v] = pk.u;
        }
    } else {
        float* dst = (float*)hout_ + ((size_t)b * T + t) * D_ + o0;
#pragma unroll
        for (int o = 0; o < DCH; ++o) dst[o] = h[o];
    }
}

// ---- root GEMV, K-split x4 --------------------------------------------------
__global__ __launch_bounds__(256, 4) void k_stage0a(const float* __restrict__ h1,
                                                    const float* __restrict__ genes0,
                                                    const float* __restrict__ W0,
                                                    float* __restrict__ z0p) {
    const int b = blockIdx.x >> 2, s = blockIdx.x & 3, tid = threadIdx.x;
    const int kbase = 640 * s;
    const float* x = h1 + (size_t)b * (T1_ * D_);
    float acc[D_] = {};
#pragma unroll
    for (int j = 0; j < 3; ++j) {
        int kl = tid + 256 * j;
        if (kl < 640) {
            int k = kbase + kl;
            float xk = x[k];
            const float4* w = (const float4*)(W0 + (size_t)k * D_);
#pragma unroll
            for (int v = 0; v < D_ / 4; ++v) {
                float4 f = w[v];
                acc[4 * v + 0] = fmaf(xk, f.x, acc[4 * v + 0]);
                acc[4 * v + 1] = fmaf(xk, f.y, acc[4 * v + 1]);
                acc[4 * v + 2] = fmaf(xk, f.z, acc[4 * v + 2]);
                acc[4 * v + 3] = fmaf(xk, f.w, acc[4 * v + 3]);
            }
        }
    }
    if (s == 3 && tid < G_) {
        float xk = genes0[(size_t)b * G_ + tid];
        const float4* w = (const float4*)(W0 + (size_t)(T1_ * D_ + tid) * D_);
#pragma unroll
        for (int v = 0; v < D_ / 4; ++v) {
            float4 f = w[v];
            acc[4 * v + 0] = fmaf(xk, f.x, acc[4 * v + 0]);
            acc[4 * v + 1] = fmaf(xk, f.y, acc[4 * v + 1]);
            acc[4 * v + 2] = fmaf(xk, f.z, acc[4 * v + 2]);
            acc[4 * v + 3] = fmaf(xk, f.w, acc[4 * v + 3]);
        }
    }
    __shared__ float sred[4][D_];
    const int lane = tid & 63, wave = tid >> 6;
#pragma unroll
    for (int off = 32; off; off >>= 1)
#pragma unroll
        for (int o = 0; o < D_; ++o) acc[o] += __shfl_xor(acc[o], off, 64);
    if (lane == 0)
#pragma unroll
        for (int o = 0; o < D_; ++o) sred[wave][o] = acc[o];
    __syncthreads();
    if (tid < D_)
        z0p[((size_t)b * 4 + s) * D_ + tid] =
            sred[0][tid] + sred[1][tid] + sred[2][tid] + sred[3][tid];
}

// ---- root BN + tanh + head --------------------------------------------------
__global__ __launch_bounds__(256) void k_stage0b(const float* __restrict__ z0p,
                                                 const float* __restrict__ g0,
                                                 const float* __restrict__ be0,
                                                 const float* __restrict__ hw0,
                                                 const float* __restrict__ hb0,
                                                 float* __restrict__ out) {
    const int tid = threadIdx.x;   // == batch row
    float acc[D_] = {};
#pragma unroll
    for (int s = 0; s < 4; ++s) {
        const float4* zp = (const float4*)(z0p + ((size_t)tid * 4 + s) * D_);
#pragma unroll
        for (int v = 0; v < D_ / 4; ++v) {
            float4 f = zp[v];
            acc[4 * v + 0] += f.x; acc[4 * v + 1] += f.y;
            acc[4 * v + 2] += f.z; acc[4 * v + 3] += f.w;
        }
    }
    float h[D_];
    bn_tanh<D_>(acc, g0, be0, 0, tid, h);
    __shared__ float hwv[D_ + 1];
    if (tid < D_) hwv[tid] = hw0[tid];
    if (tid == 0) hwv[D_] = hb0[0];
    __syncthreads();
    float pred = hwv[D_];
#pragma unroll
    for (int o = 0; o < D_; ++o) pred = fmaf(h[o], hwv[o], pred);
    out[tid] = pred;
}

extern "C" void kernel_launch(void* const* d_in, const int* in_sizes, int n_in,
                              void* d_out, int out_size, void* d_ws, size_t ws_size,
                              hipStream_t stream) {
    const float* genes3 = (const float*)d_in[0];
    const float* genes2 = (const float*)d_in[1];
    const float* genes1 = (const float*)d_in[2];
    const float* genes0 = (const float*)d_in[3];
    const float* W3  = (const float*)d_in[4];
    const float* g3  = (const float*)d_in[6];
    const float* be3 = (const float*)d_in[7];
    const float* W2  = (const float*)d_in[8];
    const float* g2  = (const float*)d_in[10];
    const float* be2 = (const float*)d_in[11];
    const float* W1  = (const float*)d_in[12];
    const float* g1  = (const float*)d_in[14];
    const float* be1 = (const float*)d_in[15];
    const float* W0  = (const float*)d_in[16];
    const float* g0  = (const float*)d_in[18];
    const float* be0 = (const float*)d_in[19];
    const float* hw0 = (const float*)d_in[20];
    const float* hb0 = (const float*)d_in[21];

    char* wsb = (char*)d_ws;
    __half* gT3 = (__half*)(wsb + OFF_GT3);
    __half* gT2 = (__half*)(wsb + OFF_GT2);
    __half* gT1 = (__half*)(wsb + OFF_GT1);
    __half* h3  = (__half*)(wsb + OFF_H3B);
    __half* h2  = (__half*)(wsb + OFF_H2B);
    float*  h1  = (float*)(wsb + OFF_H1B);
    float*  z0p = (float*)(wsb + OFF_Z0B);

    k_transpose<T3_><<<T3_, 256, 0, stream>>>(genes3, gT3);
    k_transpose<T2_><<<T2_, 256, 0, stream>>>(genes2, gT2);
    k_transpose<T1_><<<T1_, 256, 0, stream>>>(genes1, gT1);

    k_stage3<<<T3_, 256, 0, stream>>>(gT3, W3, g3, be3, h3);
    k_mid<T2_, 10, true ><<<T2_ * 2, 256, 0, stream>>>(h3, gT2, W2, g2, be2, h2);
    k_mid<T1_, 4,  false><<<T1_ * 5, 256, 0, stream>>>(h2, gT1, W1, g1, be1, h1);
    k_stage0a<<<B_ * 4, 256, 0, stream>>>(h1, genes0, W0, z0p);
    k_stage0b<<<1, 256, 0, stream>>>(z0p, g0, be0, hw0, hb0, (float*)d_out);
}

// Round 7
// 366.932 us; speedup vs baseline: 1.0323x; 1.0323x over previous
//
#include <hip/hip_runtime.h>
#include <hip/hip_fp16.h>

// DCell forward, MI355X (gfx950). All inputs/outputs fp32.
// R7: compute kernels moved to MFMA 16x16x32 f16. Per term t:
//   Z[256 x 20] = X[256 x K] * W[K x 20],  N padded to 32 (2 tiles of 16).
// A-fragments load DIRECTLY from global (term-major fp16 rows => 16B chunks);
// children are padded to K=32 each (A garbage beyond o'=20 is finite and hits
// zero-padded WT rows). Only W is staged in LDS (transposed WT[o][k], padded
// row stride => <=2-way bank conflicts). This kills the R5/R6 LDS broadcast
// storm (160-360 ds_read_b128 per thread -> ~32 per wave).
// BN is block-local (256 rows per term); bias cancels in BN => never read.
// ws: [gT3 | gT2 | gT1 | h3 | h2 | h1 | z0p] ~117 MB.

#define DEV static __device__ __forceinline__

constexpr int B_  = 256, G_ = 64, D_ = 20;
constexpr int T3_ = 2048, T2_ = 512, T1_ = 128;
constexpr float EPS_ = 1e-5f;

constexpr size_t OFF_GT3 = 0;
constexpr size_t SZ_GT3 = (size_t)T3_ * B_ * G_ * 2;
constexpr size_t OFF_GT2 = OFF_GT3 + SZ_GT3;
constexpr size_t SZ_GT2 = (size_t)T2_ * B_ * G_ * 2;
constexpr size_t OFF_GT1 = OFF_GT2 + SZ_GT2;
constexpr size_t SZ_GT1 = (size_t)T1_ * B_ * G_ * 2;
constexpr size_t OFF_H3B = OFF_GT1 + SZ_GT1;
constexpr size_t SZ_H3 = (size_t)T3_ * B_ * D_ * 2;
constexpr size_t OFF_H2B = OFF_H3B + SZ_H3;
constexpr size_t SZ_H2 = (size_t)T2_ * B_ * D_ * 2;
constexpr size_t OFF_H1B = OFF_H2B + SZ_H2;
constexpr size_t SZ_H1 = (size_t)B_ * T1_ * D_ * 4;
constexpr size_t OFF_Z0B = OFF_H1B + SZ_H1;

typedef _Float16 half8_t __attribute__((ext_vector_type(8)));
typedef float f32x4 __attribute__((ext_vector_type(4)));

DEV half8_t as_h8(uint4 u) {
    union { uint4 u4; half8_t h; } c; c.u4 = u; return c.h;
}

DEV float fast_tanh(float x) {
    float e = __expf(2.0f * x);
    return fmaf(-2.0f, __builtin_amdgcn_rcpf(e + 1.0f), 1.0f);
}

// ---- transpose: genes fp32 [256][T][64] -> gT fp16 [t][b][64] ---------------
template <int T>
__global__ __launch_bounds__(256, 4) void k_transpose(const float* __restrict__ genes,
                                                      __half* __restrict__ gT) {
    __shared__ uint lds[64 * 4 * 33];
    const int b0 = (blockIdx.x & 3) * 64;
    const int t0 = (blockIdx.x >> 2) * 4;
    const int tid = threadIdx.x, w = tid >> 6, l = tid & 63;
#pragma unroll
    for (int i = 0; i < 16; ++i) {
        const int b_loc = w * 16 + i;
        float4 f = ((const float4*)(genes + ((size_t)(b0 + b_loc) * T + t0) * G_))[l];
        const int t = l >> 4, g4 = l & 15;
        union { __half2 h; uint u; } a, c;
        a.h = __floats2half2_rn(f.x, f.y);
        c.h = __floats2half2_rn(f.z, f.w);
        uint* row = lds + (b_loc * 4 + t) * 33;
        row[2 * g4]     = a.u;
        row[2 * g4 + 1] = c.u;
    }
    __syncthreads();
#pragma unroll
    for (int r = 0; r < 8; ++r) {
        const int M = tid + 256 * r;
        const int t = M >> 9, b = (M >> 3) & 63, u4 = M & 7;
        const uint* row = lds + (b * 4 + t) * 33 + 4 * u4;
        uint4 v = make_uint4(row[0], row[1], row[2], row[3]);
        ((uint4*)(gT + (((size_t)(t0 + t) * B_) + b0 + b) * G_))[u4] = v;
    }
}

// ---- MFMA GEMM + BN + tanh for strata 3/2/1 ---------------------------------
// NCHILD children (term-major fp16 [child][b][20]) + 64 genes (gT [t][b][64]).
// K_lds = NCHILD*32 (child c padded 20->32) + 64.  NK = NCHILD + 2 k-steps.
template <int T, int NCHILD, bool OUT_HALF>
__global__ __launch_bounds__(256, 4) void k_gemm(const __half* __restrict__ hsrc,
                                                 const __half* __restrict__ gT,
                                                 const float* __restrict__ W,
                                                 const float* __restrict__ g,
                                                 const float* __restrict__ be,
                                                 void* __restrict__ hout_) {
    constexpr int K_IN = NCHILD * 20 + 64;
    constexpr int NK = NCHILD + 2;
    constexpr int STRB = NCHILD ? 200 : 72;          // WT row stride in halfs
    __shared__ __half WT[32 * STRB];
    __shared__ float gv[D_], bev[D_];
    __shared__ float sred[4][16], qred[4][16];

    const int t = blockIdx.x, tid = threadIdx.x;

    // zero WT (pad rows/cols), then scatter-fill real weights
    uint* WTu = (uint*)WT;
    for (int j = tid; j < 32 * STRB / 2; j += 256) WTu[j] = 0;
    if (tid < D_) { gv[tid] = g[t * D_ + tid]; bev[tid] = be[t * D_ + tid]; }
    __syncthreads();
    const float* Wt = W + (size_t)t * (K_IN * D_);
    for (int j = tid; j < K_IN * D_; j += 256) {
        int k_orig = j / D_, o = j - k_orig * D_;
        int k_lds;
        if (NCHILD && k_orig < NCHILD * D_) {
            int c = k_orig / D_;
            k_lds = c * 32 + (k_orig - c * D_);
        } else {
            k_lds = NCHILD * 32 + (k_orig - NCHILD * D_);
        }
        WT[o * STRB + k_lds] = __float2half(Wt[j]);
    }
    __syncthreads();

    const int w = tid >> 6, lane = tid & 63;
    const int quad = lane >> 4, l15 = lane & 15;
    const int nt = w >> 1, mhalf = w & 1;
    const int ocol = nt * 16 + l15;                   // 0..31, valid < 20
    const int brow_base = mhalf * 128;                // 8 m-tiles of 16 rows

    // B-fragments: WT[o = ocol][k = ks*32 + quad*8 + j]
    half8_t Bf[NK];
#pragma unroll
    for (int ks = 0; ks < NK; ++ks)
        Bf[ks] = as_h8(*(const uint4*)(WT + ocol * STRB + ks * 32 + quad * 8));

    f32x4 acc[8];
#pragma unroll
    for (int mt = 0; mt < 8; ++mt) acc[mt] = (f32x4){0.f, 0.f, 0.f, 0.f};

#pragma unroll
    for (int mt = 0; mt < 8; ++mt) {
        const int bA = brow_base + mt * 16 + l15;     // A-operand row = lane&15
#pragma unroll
        for (int c = 0; c < NCHILD; ++c) {
            // h3 row is 20 halfs; quad*8 may run past 20 into the next row:
            // finite garbage x zero-padded WT => exact 0 contribution.
            const __half* ap = hsrc + ((size_t)(NCHILD * t + c) * B_ + bA) * D_ + quad * 8;
            uint2 u0 = *(const uint2*)(ap);
            uint2 u1 = *(const uint2*)(ap + 4);
            acc[mt] = __builtin_amdgcn_mfma_f32_16x16x32_f16(
                as_h8(make_uint4(u0.x, u0.y, u1.x, u1.y)), Bf[c], acc[mt], 0, 0, 0);
        }
        const __half* gp = gT + ((size_t)t * B_ + bA) * G_ + quad * 8;
#pragma unroll
        for (int ks = 0; ks < 2; ++ks) {
            uint4 au = *(const uint4*)(gp + ks * 32);
            acc[mt] = __builtin_amdgcn_mfma_f32_16x16x32_f16(
                as_h8(au), Bf[NCHILD + ks], acc[mt], 0, 0, 0);
        }
    }

    // BN stats over batch: C/D layout row = quad*4+r, col = l15.
    float s = 0.f, q = 0.f;
#pragma unroll
    for (int mt = 0; mt < 8; ++mt)
#pragma unroll
        for (int r = 0; r < 4; ++r) {
            float z = acc[mt][r];
            s += z; q += z * z;
        }
    s += __shfl_xor(s, 16, 64); q += __shfl_xor(q, 16, 64);
    s += __shfl_xor(s, 32, 64); q += __shfl_xor(q, 32, 64);
    if (lane < 16) { sred[w][lane] = s; qred[w][lane] = q; }
    __syncthreads();
    const float S = sred[2 * nt][l15] + sred[2 * nt + 1][l15];
    const float Q = qred[2 * nt][l15] + qred[2 * nt + 1][l15];
    const float mu  = S * (1.0f / B_);
    const float var = fmaxf(Q * (1.0f / B_) - mu * mu, 0.0f);
    const float rstd = rsqrtf(var + EPS_);
    const int oc = ocol < D_ ? ocol : D_ - 1;
    const float A = rstd * gv[oc];
    const float C = bev[oc] - mu * A;

    if (ocol < D_) {
#pragma unroll
        for (int mt = 0; mt < 8; ++mt)
#pragma unroll
            for (int r = 0; r < 4; ++r) {
                float h = fast_tanh(fmaf(A, acc[mt][r], C));
                int b = brow_base + mt * 16 + quad * 4 + r;
                if (OUT_HALF) {
                    ((__half*)hout_)[((size_t)t * B_ + b) * D_ + ocol] = __float2half(h);
                } else {
                    ((float*)hout_)[((size_t)b * T + t) * D_ + ocol] = h;
                }
            }
    }
}

// ---- root GEMV, K-split x4 --------------------------------------------------
__global__ __launch_bounds__(256, 4) void k_stage0a(const float* __restrict__ h1,
                                                    const float* __restrict__ genes0,
                                                    const float* __restrict__ W0,
                                                    float* __restrict__ z0p) {
    const int b = blockIdx.x >> 2, s = blockIdx.x & 3, tid = threadIdx.x;
    const int kbase = 640 * s;
    const float* x = h1 + (size_t)b * (T1_ * D_);
    float acc[D_] = {};
#pragma unroll
    for (int j = 0; j < 3; ++j) {
        int kl = tid + 256 * j;
        if (kl < 640) {
            int k = kbase + kl;
            float xk = x[k];
            const float4* w = (const float4*)(W0 + (size_t)k * D_);
#pragma unroll
            for (int v = 0; v < D_ / 4; ++v) {
                float4 f = w[v];
                acc[4 * v + 0] = fmaf(xk, f.x, acc[4 * v + 0]);
                acc[4 * v + 1] = fmaf(xk, f.y, acc[4 * v + 1]);
                acc[4 * v + 2] = fmaf(xk, f.z, acc[4 * v + 2]);
                acc[4 * v + 3] = fmaf(xk, f.w, acc[4 * v + 3]);
            }
        }
    }
    if (s == 3 && tid < G_) {
        float xk = genes0[(size_t)b * G_ + tid];
        const float4* w = (const float4*)(W0 + (size_t)(T1_ * D_ + tid) * D_);
#pragma unroll
        for (int v = 0; v < D_ / 4; ++v) {
            float4 f = w[v];
            acc[4 * v + 0] = fmaf(xk, f.x, acc[4 * v + 0]);
            acc[4 * v + 1] = fmaf(xk, f.y, acc[4 * v + 1]);
            acc[4 * v + 2] = fmaf(xk, f.z, acc[4 * v + 2]);
            acc[4 * v + 3] = fmaf(xk, f.w, acc[4 * v + 3]);
        }
    }
    __shared__ float sred[4][D_];
    const int lane = tid & 63, wave = tid >> 6;
#pragma unroll
    for (int off = 32; off; off >>= 1)
#pragma unroll
        for (int o = 0; o < D_; ++o) acc[o] += __shfl_xor(acc[o], off, 64);
    if (lane == 0)
#pragma unroll
        for (int o = 0; o < D_; ++o) sred[wave][o] = acc[o];
    __syncthreads();
    if (tid < D_)
        z0p[((size_t)b * 4 + s) * D_ + tid] =
            sred[0][tid] + sred[1][tid] + sred[2][tid] + sred[3][tid];
}

// ---- root BN + tanh + head --------------------------------------------------
__global__ __launch_bounds__(256) void k_stage0b(const float* __restrict__ z0p,
                                                 const float* __restrict__ g0,
                                                 const float* __restrict__ be0,
                                                 const float* __restrict__ hw0,
                                                 const float* __restrict__ hb0,
                                                 float* __restrict__ out) {
    const int tid = threadIdx.x;   // == batch row
    float acc[D_] = {};
#pragma unroll
    for (int s = 0; s < 4; ++s) {
        const float4* zp = (const float4*)(z0p + ((size_t)tid * 4 + s) * D_);
#pragma unroll
        for (int v = 0; v < D_ / 4; ++v) {
            float4 f = zp[v];
            acc[4 * v + 0] += f.x; acc[4 * v + 1] += f.y;
            acc[4 * v + 2] += f.z; acc[4 * v + 3] += f.w;
        }
    }
    __shared__ float sred[4][D_], qred[4][D_], Avec[D_], Cvec[D_], hwv[D_ + 1];
    const int lane = tid & 63, wave = tid >> 6;
    float s[D_], q[D_];
#pragma unroll
    for (int o = 0; o < D_; ++o) { s[o] = acc[o]; q[o] = acc[o] * acc[o]; }
#pragma unroll
    for (int off = 32; off; off >>= 1) {
#pragma unroll
        for (int o = 0; o < D_; ++o) {
            s[o] += __shfl_xor(s[o], off, 64);
            q[o] += __shfl_xor(q[o], off, 64);
        }
    }
    if (lane == 0) {
#pragma unroll
        for (int o = 0; o < D_; ++o) { sred[wave][o] = s[o]; qred[wave][o] = q[o]; }
    }
    __syncthreads();
    if (tid < D_) {
        float S = sred[0][tid] + sred[1][tid] + sred[2][tid] + sred[3][tid];
        float Q = qred[0][tid] + qred[1][tid] + qred[2][tid] + qred[3][tid];
        float mu  = S * (1.0f / B_);
        float var = fmaxf(Q * (1.0f / B_) - mu * mu, 0.0f);
        float rstd = rsqrtf(var + EPS_);
        float A = rstd * g0[tid];
        Avec[tid] = A;
        Cvec[tid] = be0[tid] - mu * A;
        hwv[tid] = hw0[tid];
    }
    if (tid == 0) hwv[D_] = hb0[0];
    __syncthreads();
    float pred = hwv[D_];
#pragma unroll
    for (int o = 0; o < D_; ++o) {
        float h = fast_tanh(fmaf(acc[o], Avec[o], Cvec[o]));
        pred = fmaf(h, hwv[o], pred);
    }
    out[tid] = pred;
}

extern "C" void kernel_launch(void* const* d_in, const int* in_sizes, int n_in,
                              void* d_out, int out_size, void* d_ws, size_t ws_size,
                              hipStream_t stream) {
    const float* genes3 = (const float*)d_in[0];
    const float* genes2 = (const float*)d_in[1];
    const float* genes1 = (const float*)d_in[2];
    const float* genes0 = (const float*)d_in[3];
    const float* W3  = (const float*)d_in[4];
    const float* g3  = (const float*)d_in[6];
    const float* be3 = (const float*)d_in[7];
    const float* W2  = (const float*)d_in[8];
    const float* g2  = (const float*)d_in[10];
    const float* be2 = (const float*)d_in[11];
    const float* W1  = (const float*)d_in[12];
    const float* g1  = (const float*)d_in[14];
    const float* be1 = (const float*)d_in[15];
    const float* W0  = (const float*)d_in[16];
    const float* g0  = (const float*)d_in[18];
    const float* be0 = (const float*)d_in[19];
    const float* hw0 = (const float*)d_in[20];
    const float* hb0 = (const float*)d_in[21];

    char* wsb = (char*)d_ws;
    __half* gT3 = (__half*)(wsb + OFF_GT3);
    __half* gT2 = (__half*)(wsb + OFF_GT2);
    __half* gT1 = (__half*)(wsb + OFF_GT1);
    __half* h3  = (__half*)(wsb + OFF_H3B);
    __half* h2  = (__half*)(wsb + OFF_H2B);
    float*  h1  = (float*)(wsb + OFF_H1B);
    float*  z0p = (float*)(wsb + OFF_Z0B);

    k_transpose<T3_><<<T3_, 256, 0, stream>>>(genes3, gT3);
    k_transpose<T2_><<<T2_, 256, 0, stream>>>(genes2, gT2);
    k_transpose<T1_><<<T1_, 256, 0, stream>>>(genes1, gT1);

    k_gemm<T3_, 0, true ><<<T3_, 256, 0, stream>>>(nullptr, gT3, W3, g3, be3, h3);
    k_gemm<T2_, 4, true ><<<T2_, 256, 0, stream>>>(h3, gT2, W2, g2, be2, h2);
    k_gemm<T1_, 4, false><<<T1_, 256, 0, stream>>>(h2, gT1, W1, g1, be1, h1);
    k_stage0a<<<B_ * 4, 256, 0, stream>>>(h1, genes0, W0, z0p);
    k_stage0b<<<1, 256, 0, stream>>>(z0p, g0, be0, hw0, hb0, (float*)d_out);
}

// Round 8
// 341.845 us; speedup vs baseline: 1.1080x; 1.0734x over previous
//
#include <hip/hip_runtime.h>
#include <hip/hip_fp16.h>

// DCell forward, MI355X (gfx950). All inputs/outputs fp32.
// R8: genes are exactly {0,1} => transpose to u8 (half the gT bytes of R7),
// one merged transpose kernel for all 3 strata; gemm A-fragments for genes
// load 8 bytes and expand to half8 via exact bit trick ((b0|b1<<16)*0x3C00).
// Compute: MFMA 16x16x32 f16 per term (R7 structure, passed).
// BN block-local; linear bias cancels in BN => never read.
// ws: [gT3 u8 33.5MB | gT2 8.4 | gT1 2.1 | h3 fp16 21 | h2 5.2 | h1 fp32 2.6 | z0p].

#define DEV static __device__ __forceinline__

constexpr int B_  = 256, G_ = 64, D_ = 20;
constexpr int T3_ = 2048, T2_ = 512, T1_ = 128;
constexpr float EPS_ = 1e-5f;

typedef unsigned char u8;

constexpr size_t OFF_GT3 = 0;
constexpr size_t SZ_GT3 = (size_t)T3_ * B_ * G_;
constexpr size_t OFF_GT2 = OFF_GT3 + SZ_GT3;
constexpr size_t SZ_GT2 = (size_t)T2_ * B_ * G_;
constexpr size_t OFF_GT1 = OFF_GT2 + SZ_GT2;
constexpr size_t SZ_GT1 = (size_t)T1_ * B_ * G_;
constexpr size_t OFF_H3B = OFF_GT1 + SZ_GT1;
constexpr size_t SZ_H3 = (size_t)T3_ * B_ * D_ * 2;
constexpr size_t OFF_H2B = OFF_H3B + SZ_H3;
constexpr size_t SZ_H2 = (size_t)T2_ * B_ * D_ * 2;
constexpr size_t OFF_H1B = OFF_H2B + SZ_H2;
constexpr size_t SZ_H1 = (size_t)B_ * T1_ * D_ * 4;
constexpr size_t OFF_Z0B = OFF_H1B + SZ_H1;

typedef _Float16 half8_t __attribute__((ext_vector_type(8)));
typedef float f32x4 __attribute__((ext_vector_type(4)));

DEV half8_t as_h8(uint4 u) {
    union { uint4 u4; half8_t h; } c; c.u4 = u; return c.h;
}

// 8 gene bytes (each 0/1) -> half8 {0.0h, 1.0h}. Exact: no carries possible.
DEV half8_t u8x8_to_h8(uint2 v) {
    uint4 r;
    uint x = v.x;
    r.x = ((x & 0xFFu) | ((x & 0xFF00u) << 8)) * 0x3C00u;
    r.y = (((x >> 16) & 0xFFu) | ((x >> 8) & 0xFF0000u)) * 0x3C00u;
    x = v.y;
    r.z = ((x & 0xFFu) | ((x & 0xFF00u) << 8)) * 0x3C00u;
    r.w = (((x >> 16) & 0xFFu) | ((x >> 8) & 0xFF0000u)) * 0x3C00u;
    return as_h8(r);
}

DEV float fast_tanh(float x) {
    float e = __expf(2.0f * x);
    return fmaf(-2.0f, __builtin_amdgcn_rcpf(e + 1.0f), 1.0f);
}

// ---- merged transpose: genes fp32 [256][T][64] -> gT u8 [t][b][64] ----------
// Block tile: 64 b x 4 t. Reads 1-KB dense bursts; writes 16-B/lane dense.
__global__ __launch_bounds__(256, 4) void k_transpose_all(
        const float* __restrict__ g3s, const float* __restrict__ g2s,
        const float* __restrict__ g1s,
        u8* __restrict__ d3, u8* __restrict__ d2, u8* __restrict__ d1) {
    __shared__ uint lds[64 * 4 * 17];          // (b_loc*4+t) rows of 16 uints + pad
    int blk = blockIdx.x;
    const float* src; u8* dst; int T;
    if (blk < T3_)              { src = g3s; dst = d3; T = T3_; }
    else if (blk < T3_ + T2_)   { blk -= T3_; src = g2s; dst = d2; T = T2_; }
    else                        { blk -= T3_ + T2_; src = g1s; dst = d1; T = T1_; }
    const int b0 = (blk & 3) * 64;
    const int t0 = (blk >> 2) * 4;
    const int tid = threadIdx.x, w = tid >> 6, l = tid & 63;
#pragma unroll
    for (int i = 0; i < 16; ++i) {
        const int b_loc = w * 16 + i;
        // slice genes[b0+b_loc][t0:t0+4][0:64] = 256 floats; lane l -> float4 #l
        float4 f = ((const float4*)(src + ((size_t)(b0 + b_loc) * T + t0) * G_))[l];
        const int t = l >> 4, g4 = l & 15;
        uint p = (uint)(u8)f.x | ((uint)(u8)f.y << 8) |
                 ((uint)(u8)f.z << 16) | ((uint)(u8)f.w << 24);
        lds[(b_loc * 4 + t) * 17 + g4] = p;
    }
    __syncthreads();
#pragma unroll
    for (int r = 0; r < 4; ++r) {
        const int M = tid + 256 * r;           // 1024 output uint4s
        const int t = M >> 8, b = (M >> 2) & 63, c = M & 3;
        const uint* row = lds + (b * 4 + t) * 17 + c * 4;
        uint4 v = make_uint4(row[0], row[1], row[2], row[3]);
        ((uint4*)(dst + (((size_t)(t0 + t) * B_) + b0 + b) * G_))[c] = v;
    }
}

// ---- MFMA GEMM + BN + tanh for strata 3/2/1 ---------------------------------
// NCHILD children (term-major fp16 [child][b][20]) + 64 genes (gT u8 [t][b][64]).
template <int T, int NCHILD, bool OUT_HALF>
__global__ __launch_bounds__(256, 4) void k_gemm(const __half* __restrict__ hsrc,
                                                 const u8* __restrict__ gT,
                                                 const float* __restrict__ W,
                                                 const float* __restrict__ g,
                                                 const float* __restrict__ be,
                                                 void* __restrict__ hout_) {
    constexpr int K_IN = NCHILD * 20 + 64;
    constexpr int NK = NCHILD + 2;
    constexpr int STRB = NCHILD ? 200 : 72;          // WT row stride in halfs
    __shared__ __half WT[32 * STRB];
    __shared__ float gv[D_], bev[D_];
    __shared__ float sred[4][16], qred[4][16];

    const int t = blockIdx.x, tid = threadIdx.x;

    uint* WTu = (uint*)WT;
    for (int j = tid; j < 32 * STRB / 2; j += 256) WTu[j] = 0;
    if (tid < D_) { gv[tid] = g[t * D_ + tid]; bev[tid] = be[t * D_ + tid]; }
    __syncthreads();
    const float* Wt = W + (size_t)t * (K_IN * D_);
    for (int j = tid; j < K_IN * D_; j += 256) {
        int k_orig = j / D_, o = j - k_orig * D_;
        int k_lds;
        if (NCHILD && k_orig < NCHILD * D_) {
            int c = k_orig / D_;
            k_lds = c * 32 + (k_orig - c * D_);
        } else {
            k_lds = NCHILD * 32 + (k_orig - NCHILD * D_);
        }
        WT[o * STRB + k_lds] = __float2half(Wt[j]);
    }
    __syncthreads();

    const int w = tid >> 6, lane = tid & 63;
    const int quad = lane >> 4, l15 = lane & 15;
    const int nt = w >> 1, mhalf = w & 1;
    const int ocol = nt * 16 + l15;                   // 0..31, valid < 20
    const int brow_base = mhalf * 128;                // 8 m-tiles of 16 rows

    half8_t Bf[NK];
#pragma unroll
    for (int ks = 0; ks < NK; ++ks)
        Bf[ks] = as_h8(*(const uint4*)(WT + ocol * STRB + ks * 32 + quad * 8));

    f32x4 acc[8];
#pragma unroll
    for (int mt = 0; mt < 8; ++mt) acc[mt] = (f32x4){0.f, 0.f, 0.f, 0.f};

#pragma unroll
    for (int mt = 0; mt < 8; ++mt) {
        const int bA = brow_base + mt * 16 + l15;     // A-operand row = lane&15
#pragma unroll
        for (int c = 0; c < NCHILD; ++c) {
            // h row is 20 halfs; quad*8 may run past 20 into the next row:
            // finite garbage x zero-padded WT => exact 0 contribution.
            const __half* ap = hsrc + ((size_t)(NCHILD * t + c) * B_ + bA) * D_ + quad * 8;
            uint2 u0 = *(const uint2*)(ap);
            uint2 u1 = *(const uint2*)(ap + 4);
            acc[mt] = __builtin_amdgcn_mfma_f32_16x16x32_f16(
                as_h8(make_uint4(u0.x, u0.y, u1.x, u1.y)), Bf[c], acc[mt], 0, 0, 0);
        }
        const u8* gp = gT + ((size_t)t * B_ + bA) * G_ + quad * 8;
#pragma unroll
        for (int ks = 0; ks < 2; ++ks) {
            uint2 au = *(const uint2*)(gp + ks * 32);
            acc[mt] = __builtin_amdgcn_mfma_f32_16x16x32_f16(
                u8x8_to_h8(au), Bf[NCHILD + ks], acc[mt], 0, 0, 0);
        }
    }

    // BN stats over batch: C/D layout row = quad*4+r, col = l15.
    float s = 0.f, q = 0.f;
#pragma unroll
    for (int mt = 0; mt < 8; ++mt)
#pragma unroll
        for (int r = 0; r < 4; ++r) {
            float z = acc[mt][r];
            s += z; q += z * z;
        }
    s += __shfl_xor(s, 16, 64); q += __shfl_xor(q, 16, 64);
    s += __shfl_xor(s, 32, 64); q += __shfl_xor(q, 32, 64);
    if (lane < 16) { sred[w][lane] = s; qred[w][lane] = q; }
    __syncthreads();
    const float S = sred[2 * nt][l15] + sred[2 * nt + 1][l15];
    const float Q = qred[2 * nt][l15] + qred[2 * nt + 1][l15];
    const float mu  = S * (1.0f / B_);
    const float var = fmaxf(Q * (1.0f / B_) - mu * mu, 0.0f);
    const float rstd = rsqrtf(var + EPS_);
    const int oc = ocol < D_ ? ocol : D_ - 1;
    const float A = rstd * gv[oc];
    const float C = bev[oc] - mu * A;

    if (ocol < D_) {
#pragma unroll
        for (int mt = 0; mt < 8; ++mt)
#pragma unroll
            for (int r = 0; r < 4; ++r) {
                float h = fast_tanh(fmaf(A, acc[mt][r], C));
                int b = brow_base + mt * 16 + quad * 4 + r;
                if (OUT_HALF) {
                    ((__half*)hout_)[((size_t)t * B_ + b) * D_ + ocol] = __float2half(h);
                } else {
                    ((float*)hout_)[((size_t)b * T + t) * D_ + ocol] = h;
                }
            }
    }
}

// ---- root GEMV, K-split x4 --------------------------------------------------
__global__ __launch_bounds__(256, 4) void k_stage0a(const float* __restrict__ h1,
                                                    const float* __restrict__ genes0,
                                                    const float* __restrict__ W0,
                                                    float* __restrict__ z0p) {
    const int b = blockIdx.x >> 2, s = blockIdx.x & 3, tid = threadIdx.x;
    const int kbase = 640 * s;
    const float* x = h1 + (size_t)b * (T1_ * D_);
    float acc[D_] = {};
#pragma unroll
    for (int j = 0; j < 3; ++j) {
        int kl = tid + 256 * j;
        if (kl < 640) {
            int k = kbase + kl;
            float xk = x[k];
            const float4* w = (const float4*)(W0 + (size_t)k * D_);
#pragma unroll
            for (int v = 0; v < D_ / 4; ++v) {
                float4 f = w[v];
                acc[4 * v + 0] = fmaf(xk, f.x, acc[4 * v + 0]);
                acc[4 * v + 1] = fmaf(xk, f.y, acc[4 * v + 1]);
                acc[4 * v + 2] = fmaf(xk, f.z, acc[4 * v + 2]);
                acc[4 * v + 3] = fmaf(xk, f.w, acc[4 * v + 3]);
            }
        }
    }
    if (s == 3 && tid < G_) {
        float xk = genes0[(size_t)b * G_ + tid];
        const float4* w = (const float4*)(W0 + (size_t)(T1_ * D_ + tid) * D_);
#pragma unroll
        for (int v = 0; v < D_ / 4; ++v) {
            float4 f = w[v];
            acc[4 * v + 0] = fmaf(xk, f.x, acc[4 * v + 0]);
            acc[4 * v + 1] = fmaf(xk, f.y, acc[4 * v + 1]);
            acc[4 * v + 2] = fmaf(xk, f.z, acc[4 * v + 2]);
            acc[4 * v + 3] = fmaf(xk, f.w, acc[4 * v + 3]);
        }
    }
    __shared__ float sred[4][D_];
    const int lane = tid & 63, wave = tid >> 6;
#pragma unroll
    for (int off = 32; off; off >>= 1)
#pragma unroll
        for (int o = 0; o < D_; ++o) acc[o] += __shfl_xor(acc[o], off, 64);
    if (lane == 0)
#pragma unroll
        for (int o = 0; o < D_; ++o) sred[wave][o] = acc[o];
    __syncthreads();
    if (tid < D_)
        z0p[((size_t)b * 4 + s) * D_ + tid] =
            sred[0][tid] + sred[1][tid] + sred[2][tid] + sred[3][tid];
}

// ---- root BN + tanh + head --------------------------------------------------
__global__ __launch_bounds__(256) void k_stage0b(const float* __restrict__ z0p,
                                                 const float* __restrict__ g0,
                                                 const float* __restrict__ be0,
                                                 const float* __restrict__ hw0,
                                                 const float* __restrict__ hb0,
                                                 float* __restrict__ out) {
    const int tid = threadIdx.x;   // == batch row
    float acc[D_] = {};
#pragma unroll
    for (int s = 0; s < 4; ++s) {
        const float4* zp = (const float4*)(z0p + ((size_t)tid * 4 + s) * D_);
#pragma unroll
        for (int v = 0; v < D_ / 4; ++v) {
            float4 f = zp[v];
            acc[4 * v + 0] += f.x; acc[4 * v + 1] += f.y;
            acc[4 * v + 2] += f.z; acc[4 * v + 3] += f.w;
        }
    }
    __shared__ float sred[4][D_], qred[4][D_], Avec[D_], Cvec[D_], hwv[D_ + 1];
    const int lane = tid & 63, wave = tid >> 6;
    float s[D_], q[D_];
#pragma unroll
    for (int o = 0; o < D_; ++o) { s[o] = acc[o]; q[o] = acc[o] * acc[o]; }
#pragma unroll
    for (int off = 32; off; off >>= 1) {
#pragma unroll
        for (int o = 0; o < D_; ++o) {
            s[o] += __shfl_xor(s[o], off, 64);
            q[o] += __shfl_xor(q[o], off, 64);
        }
    }
    if (lane == 0) {
#pragma unroll
        for (int o = 0; o < D_; ++o) { sred[wave][o] = s[o]; qred[wave][o] = q[o]; }
    }
    __syncthreads();
    if (tid < D_) {
        float S = sred[0][tid] + sred[1][tid] + sred[2][tid] + sred[3][tid];
        float Q = qred[0][tid] + qred[1][tid] + qred[2][tid] + qred[3][tid];
        float mu  = S * (1.0f / B_);
        float var = fmaxf(Q * (1.0f / B_) - mu * mu, 0.0f);
        float rstd = rsqrtf(var + EPS_);
        float A = rstd * g0[tid];
        Avec[tid] = A;
        Cvec[tid] = be0[tid] - mu * A;
        hwv[tid] = hw0[tid];
    }
    if (tid == 0) hwv[D_] = hb0[0];
    __syncthreads();
    float pred = hwv[D_];
#pragma unroll
    for (int o = 0; o < D_; ++o) {
        float h = fast_tanh(fmaf(acc[o], Avec[o], Cvec[o]));
        pred = fmaf(h, hwv[o], pred);
    }
    out[tid] = pred;
}

extern "C" void kernel_launch(void* const* d_in, const int* in_sizes, int n_in,
                              void* d_out, int out_size, void* d_ws, size_t ws_size,
                              hipStream_t stream) {
    const float* genes3 = (const float*)d_in[0];
    const float* genes2 = (const float*)d_in[1];
    const float* genes1 = (const float*)d_in[2];
    const float* genes0 = (const float*)d_in[3];
    const float* W3  = (const float*)d_in[4];
    const float* g3  = (const float*)d_in[6];
    const float* be3 = (const float*)d_in[7];
    const float* W2  = (const float*)d_in[8];
    const float* g2  = (const float*)d_in[10];
    const float* be2 = (const float*)d_in[11];
    const float* W1  = (const float*)d_in[12];
    const float* g1  = (const float*)d_in[14];
    const float* be1 = (const float*)d_in[15];
    const float* W0  = (const float*)d_in[16];
    const float* g0  = (const float*)d_in[18];
    const float* be0 = (const float*)d_in[19];
    const float* hw0 = (const float*)d_in[20];
    const float* hb0 = (const float*)d_in[21];

    char* wsb = (char*)d_ws;
    u8* gT3 = (u8*)(wsb + OFF_GT3);
    u8* gT2 = (u8*)(wsb + OFF_GT2);
    u8* gT1 = (u8*)(wsb + OFF_GT1);
    __half* h3  = (__half*)(wsb + OFF_H3B);
    __half* h2  = (__half*)(wsb + OFF_H2B);
    float*  h1  = (float*)(wsb + OFF_H1B);
    float*  z0p = (float*)(wsb + OFF_Z0B);

    k_transpose_all<<<T3_ + T2_ + T1_, 256, 0, stream>>>(genes3, genes2, genes1,
                                                         gT3, gT2, gT1);
    k_gemm<T3_, 0, true ><<<T3_, 256, 0, stream>>>(nullptr, gT3, W3, g3, be3, h3);
    k_gemm<T2_, 4, true ><<<T2_, 256, 0, stream>>>(h3, gT2, W2, g2, be2, h2);
    k_gemm<T1_, 4, false><<<T1_, 256, 0, stream>>>(h2, gT1, W1, g1, be1, h1);
    k_stage0a<<<B_ * 4, 256, 0, stream>>>(h1, genes0, W0, z0p);
    k_stage0b<<<1, 256, 0, stream>>>(z0p, g0, be0, hw0, hb0, (float*)d_out);
}